// Round 6
// baseline (2160.692 us; speedup 1.0000x reference)
//
#include <hip/hip_runtime.h>

typedef __attribute__((ext_vector_type(8))) short short8;     // 8 x bf16 (4 VGPRs)
typedef __attribute__((ext_vector_type(4))) float f32x4;      // MFMA accum
typedef __attribute__((ext_vector_type(4))) int int4v;        // 16B mover

typedef const __attribute__((address_space(1))) void* gas_t;
typedef __attribute__((address_space(3))) void* las_t;

__device__ __forceinline__ unsigned short f2bf(float f) {
  unsigned int u = __float_as_uint(f);
  u += 0x7fffu + ((u >> 16) & 1u);   // RNE
  return (unsigned short)(u >> 16);
}

// ---------------- fp32 -> bf16 convert (x and enc in one launch) -----------
__global__ void cvt2_kernel(const float* __restrict__ x,
                            unsigned short* __restrict__ xo, int nxb,
                            const float* __restrict__ enc,
                            unsigned short* __restrict__ eo, int ne) {
  if ((int)blockIdx.x < nxb) {
    int i = (blockIdx.x * 256 + threadIdx.x) * 4;
    float4 v = *(const float4*)(x + i);
    ushort4 r;
    r.x = f2bf(v.x); r.y = f2bf(v.y); r.z = f2bf(v.z); r.w = f2bf(v.w);
    *(ushort4*)(xo + i) = r;
  } else {
    int i = ((blockIdx.x - nxb) * 256 + threadIdx.x) * 4;
    if (i + 3 < ne) {
      float4 v = *(const float4*)(enc + i);
      ushort4 r;
      r.x = f2bf(v.x); r.y = f2bf(v.y); r.z = f2bf(v.z); r.w = f2bf(v.w);
      *(ushort4*)(eo + i) = r;
    }
  }
}

// ---------------- all 7 weight transposes in one launch --------------------
__global__ void transpose_cvt7_kernel(
    const float* __restrict__ W0, const float* __restrict__ W1,
    const float* __restrict__ W2, const float* __restrict__ W3,
    const float* __restrict__ W4, const float* __restrict__ W5,
    const float* __restrict__ W6,
    unsigned short* __restrict__ WqcT, unsigned short* __restrict__ WkvT,
    unsigned short* __restrict__ WoT) {
  const float* W; unsigned short* Wt; int K;
  switch (blockIdx.z) {
    case 0: W = W0; Wt = WqcT;            K = 640; break;
    case 1: W = W1; Wt = WqcT + 640*640;  K = 640; break;
    case 2: W = W2; Wt = WkvT;            K = 768; break;
    case 3: W = W3; Wt = WkvT + 640*768;  K = 768; break;
    case 4: W = W4; Wt = WkvT + 1280*768; K = 768; break;
    case 5: W = W5; Wt = WkvT + 1920*768; K = 768; break;
    default: W = W6; Wt = WoT;            K = 640; break;
  }
  const int N = 640;
  int k0 = blockIdx.x * 32, n0 = blockIdx.y * 32;
  if (k0 >= K) return;   // block-uniform, before any barrier
  __shared__ float t[32][33];
  int tx = threadIdx.x & 31, ty = threadIdx.x >> 5;   // 32 x 8
  #pragma unroll
  for (int i = 0; i < 32; i += 8)
    t[ty + i][tx] = W[(size_t)(k0 + ty + i) * N + n0 + tx];
  __syncthreads();
  #pragma unroll
  for (int i = 0; i < 32; i += 8)
    Wt[(size_t)(n0 + ty + i) * K + k0 + tx] = f2bf(t[tx][ty + i]);
}

// ---------------- V transpose: KVall -> VtG[b][h][d=80][k=96] ----------------
__global__ void vtrans_kernel(const unsigned short* __restrict__ KV,
                              unsigned short* __restrict__ VtG) {
  int idx = blockIdx.x * 256 + threadIdx.x;
  if (idx >= 16 * 8 * 80 * 96) return;
  int k = idx % 96;
  int d = (idx / 96) % 80;
  int h = (idx / (96 * 80)) % 8;
  int b = idx / (96 * 80 * 8);
  unsigned short v = 0;
  if (k < 87) {
    int base = (k < 77) ? 640 : 1920;  // tv at col 640, vv at col 1920
    v = KV[(size_t)(b * 87 + k) * 2560 + base + h * 80 + d];
  }
  VtG[idx] = v;
}

// ---------------- m97-style GEMM (kept for the small KV projection) --------
template<bool F32OUT>
__global__ __launch_bounds__(256, 2) void gemm_bt_kernel(
    const unsigned short* __restrict__ A,   // M x K bf16
    const unsigned short* __restrict__ Bt,  // N x K bf16
    void* __restrict__ Cptr, const float* __restrict__ bias,
    int M, int N, int K, int NT) {          // NT = number of 128-col tiles
  __shared__ __align__(16) unsigned short smem[2 * 128 * 64];
  unsigned short* As = smem;             // 128 x 64
  unsigned short* Bs = smem + 128 * 64;  // 128 x 64 (rows = n)

  const int tid  = threadIdx.x;
  const int wave = tid >> 6, lane = tid & 63;
  const int lrow = lane & 15, quad = lane >> 4;

  const int nwg = gridDim.x;
  const int qch = nwg >> 3, rch = nwg & 7;
  const int xcd = blockIdx.x & 7;
  const int wgid = (xcd < rch ? xcd * (qch + 1)
                              : rch * (qch + 1) + (xcd - rch) * qch)
                 + (blockIdx.x >> 3);
  const int row0 = (wgid / NT) * 128, col0 = (wgid % NT) * 128;

  const int wm = (wave >> 1) * 64, wn = (wave & 1) * 64;
  const int srow = lane >> 3;          // row within 8-row group
  const int scol = (lane & 7) * 8;     // bf16 col (16B chunk)

  f32x4 zero = {0.f, 0.f, 0.f, 0.f};
  f32x4 acc[4][4];
  #pragma unroll
  for (int mi = 0; mi < 4; ++mi)
    #pragma unroll
    for (int ni = 0; ni < 4; ++ni) acc[mi][ni] = zero;

  for (int k0 = 0; k0 < K; k0 += 64) {
    #pragma unroll
    for (int i = 0; i < 4; ++i) {
      int r = (wave * 4 + i) * 8 + srow;            // 0..127
      int ga = row0 + r; if (ga > M - 1) ga = M - 1; // clamp M edge
      const unsigned short* gA = A + (size_t)ga * K + k0 + scol;
      __builtin_amdgcn_global_load_lds((gas_t)gA, (las_t)(As + r * 64 + scol), 16, 0, 0);
      const unsigned short* gB = Bt + (size_t)(col0 + r) * K + k0 + scol;
      __builtin_amdgcn_global_load_lds((gas_t)gB, (las_t)(Bs + r * 64 + scol), 16, 0, 0);
    }
    __syncthreads();
    #pragma unroll
    for (int kk = 0; kk < 64; kk += 32) {
      short8 av[4], bv[4];
      #pragma unroll
      for (int mi = 0; mi < 4; ++mi)
        av[mi] = *(const short8*)(As + (wm + mi * 16 + lrow) * 64 + kk + quad * 8);
      #pragma unroll
      for (int ni = 0; ni < 4; ++ni)
        bv[ni] = *(const short8*)(Bs + (wn + ni * 16 + lrow) * 64 + kk + quad * 8);
      #pragma unroll
      for (int mi = 0; mi < 4; ++mi)
        #pragma unroll
        for (int ni = 0; ni < 4; ++ni)
          acc[mi][ni] = __builtin_amdgcn_mfma_f32_16x16x32_bf16(av[mi], bv[ni], acc[mi][ni], 0, 0, 0);
    }
    __syncthreads();
  }

  if (F32OUT) {
    float* C = (float*)Cptr;
    #pragma unroll
    for (int mi = 0; mi < 4; ++mi)
      #pragma unroll
      for (int ni = 0; ni < 4; ++ni) {
        int col = col0 + wn + ni * 16 + lrow;
        float bv = bias[col];
        #pragma unroll
        for (int r = 0; r < 4; ++r) {
          int row = row0 + wm + mi * 16 + quad * 4 + r;
          if (row < M) C[(size_t)row * N + col] = acc[mi][ni][r] + bv;
        }
      }
  } else {
    unsigned short* C = (unsigned short*)Cptr;
    unsigned short* Cw = smem + wave * 4096;  // 64x64 region per wave
    #pragma unroll
    for (int mi = 0; mi < 4; ++mi)
      #pragma unroll
      for (int ni = 0; ni < 4; ++ni)
        #pragma unroll
        for (int r = 0; r < 4; ++r)
          Cw[(mi * 16 + quad * 4 + r) * 64 + ni * 16 + lrow] = f2bf(acc[mi][ni][r]);
    #pragma unroll
    for (int it = 0; it < 8; ++it) {
      int row = it * 8 + (lane >> 3);
      int c8  = (lane & 7) * 8;
      int grow = row0 + wm + row;
      if (grow < M) {
        int4v v = *(const int4v*)(Cw + row * 64 + c8);
        *(int4v*)(C + (size_t)grow * N + col0 + wn + c8) = v;
      }
    }
  }
}

// ---------------- 256x256 GEMM, ring-2 (64KB LDS) -> 2 blocks/CU -----------
// 512 threads = 8 waves (2M x 4N), per-wave 128x64 output, BK=32.
// Theory: at K=640 cross-block TLP beats pipeline depth. 2 co-resident
// blocks let one block's MFMA cover the other's ds_read/stage/barrier
// windows (m114 co-scheduling). Loose schedule: counted vmcnt(4), raw
// barriers, setprio around MFMA, st_16x32 LDS swizzle via pre-swizzled
// global source (rule #21), bijective XCD swizzle.
// BUGFIX r4->r5: bf16 epilogue transposes 64 rows/round through an 8KB
// wave-local region (8 waves x 8KB = 64KB exactly); the r4 version
// addressed 128KB against the 64KB allocation (waves 4-7 OOB).
template<bool F32OUT>
__global__ __launch_bounds__(512, 4) void gemm256_kernel(
    const unsigned short* __restrict__ A,   // M x K bf16
    const unsigned short* __restrict__ Bt,  // N x K bf16
    void* __restrict__ Cptr, const float* __restrict__ bias,
    int M, int N, int K, int NT) {          // NT = number of 256-col tiles
  __shared__ __align__(16) unsigned short smem[2 * 16384];  // 64 KB

  const int tid  = threadIdx.x;
  const int wave = tid >> 6, lane = tid & 63;
  const int lrow = lane & 15, quad = lane >> 4;

  // bijective XCD-chunked swizzle, N-fast linearization
  const int nwg = gridDim.x;
  const int qch = nwg >> 3, rch = nwg & 7;
  const int xcd = blockIdx.x & 7;
  const int wgid = (xcd < rch ? xcd * (qch + 1)
                              : rch * (qch + 1) + (xcd - rch) * qch)
                 + (blockIdx.x >> 3);
  const int row0 = (wgid / NT) * 256, col0 = (wgid % NT) * 256;

  const int wm = (wave >> 2) * 128;   // 0 or 128
  const int wn = (wave & 3) * 64;     // 0..192
  const int NKT = K >> 5;             // K-tiles of 32 (>= 2)

  // ---- staging source addresses (pre-swizzled global, linear LDS dest) ----
  const unsigned short* gA[2];
  const unsigned short* gB[2];
  #pragma unroll
  for (int j = 0; j < 2; ++j) {
    int P = tid * 16 + j * 8192;
    int lin = P ^ (((P >> 9) & 1) << 5);
    int r = ((P >> 10) << 4) + ((lin >> 6) & 15);   // logical row 0..255
    int c = (lin & 63) >> 1;                        // logical col 0..31
    int ga = row0 + r; if (ga > M - 1) ga = M - 1;
    int gb = col0 + r; if (gb > N - 1) gb = N - 1;  // clamp (O-gemm pad tile)
    gA[j] = A  + (size_t)ga * K + c;
    gB[j] = Bt + (size_t)gb * K + c;
  }

  // ---- fragment read offsets (shorts), with st_16x32 XOR ----
  const int xorb = ((lrow >> 3) & 1) << 4;   // byte-bit5 == short-bit4
  int offA[8], offB[4];
  #pragma unroll
  for (int mi = 0; mi < 8; ++mi)
    offA[mi] = (((((wm >> 4) + mi) << 9) + (lrow << 5) + (quad << 3))) ^ xorb;
  #pragma unroll
  for (int ni = 0; ni < 4; ++ni)
    offB[ni] = (((((wn >> 4) + ni) << 9) + (lrow << 5) + (quad << 3))) ^ xorb;

  f32x4 zero = {0.f, 0.f, 0.f, 0.f};
  f32x4 acc[8][4];
  #pragma unroll
  for (int mi = 0; mi < 8; ++mi)
    #pragma unroll
    for (int ni = 0; ni < 4; ++ni) acc[mi][ni] = zero;

  // ---- prologue: stage tiles 0 and 1 ----
  #pragma unroll
  for (int t = 0; t < 2; ++t) {
    unsigned short* slot = smem + t * 16384;
    #pragma unroll
    for (int j = 0; j < 2; ++j)
      __builtin_amdgcn_global_load_lds((gas_t)(gA[j] + t * 32),
          (las_t)(slot + j * 4096 + tid * 8), 16, 0, 0);
    #pragma unroll
    for (int j = 0; j < 2; ++j)
      __builtin_amdgcn_global_load_lds((gas_t)(gB[j] + t * 32),
          (las_t)(slot + 8192 + j * 4096 + tid * 8), 16, 0, 0);
  }

  // ---- main loop ----
  for (int t = 0; t < NKT; ++t) {
    // drain tile t's stage (leave tile t+1's 4 loads in flight)
    if (t + 1 < NKT) asm volatile("s_waitcnt vmcnt(4)" ::: "memory");
    else             asm volatile("s_waitcnt vmcnt(0)" ::: "memory");
    __builtin_amdgcn_s_barrier();          // (A) slot t&1 visible to all

    const unsigned short* As = smem + (t & 1) * 16384;
    const unsigned short* Bs = As + 8192;

    short8 av0[4], bv[4];
    #pragma unroll
    for (int mi = 0; mi < 4; ++mi) av0[mi] = *(const short8*)(As + offA[mi]);
    #pragma unroll
    for (int ni = 0; ni < 4; ++ni) bv[ni] = *(const short8*)(Bs + offB[ni]);
    __builtin_amdgcn_s_setprio(1);
    #pragma unroll
    for (int mi = 0; mi < 4; ++mi)
      #pragma unroll
      for (int ni = 0; ni < 4; ++ni)
        acc[mi][ni] = __builtin_amdgcn_mfma_f32_16x16x32_bf16(av0[mi], bv[ni], acc[mi][ni], 0, 0, 0);
    __builtin_amdgcn_s_setprio(0);

    short8 av1[4];
    #pragma unroll
    for (int mi = 0; mi < 4; ++mi) av1[mi] = *(const short8*)(As + offA[4 + mi]);
    __builtin_amdgcn_s_setprio(1);
    #pragma unroll
    for (int mi = 0; mi < 4; ++mi)
      #pragma unroll
      for (int ni = 0; ni < 4; ++ni)
        acc[4 + mi][ni] = __builtin_amdgcn_mfma_f32_16x16x32_bf16(av1[mi], bv[ni], acc[4 + mi][ni], 0, 0, 0);
    __builtin_amdgcn_s_setprio(0);

    __builtin_amdgcn_s_barrier();          // (B) all waves done reading slot t&1

    if (t + 2 < NKT) {                     // refill just-freed slot with tile t+2
      unsigned short* nslot = smem + (t & 1) * 16384;
      #pragma unroll
      for (int j = 0; j < 2; ++j)
        __builtin_amdgcn_global_load_lds((gas_t)(gA[j] + (t + 2) * 32),
            (las_t)(nslot + j * 4096 + tid * 8), 16, 0, 0);
      #pragma unroll
      for (int j = 0; j < 2; ++j)
        __builtin_amdgcn_global_load_lds((gas_t)(gB[j] + (t + 2) * 32),
            (las_t)(nslot + 8192 + j * 4096 + tid * 8), 16, 0, 0);
    }
  }

  // ---- epilogue (loop-final barrier (B) protects smem reuse) ----
  if (F32OUT) {
    float* C = (float*)Cptr;
    #pragma unroll
    for (int mi = 0; mi < 8; ++mi)
      #pragma unroll
      for (int ni = 0; ni < 4; ++ni) {
        int col = col0 + wn + ni * 16 + lrow;
        int colc = col < N ? col : 0;
        float bval = bias[colc];
        #pragma unroll
        for (int r = 0; r < 4; ++r) {
          int row = row0 + wm + mi * 16 + quad * 4 + r;
          if (col < N && row < M)
            C[(size_t)row * N + col] = acc[mi][ni][r] + bval;
        }
      }
  } else {
    unsigned short* C = (unsigned short*)Cptr;
    unsigned short* Cw = smem + wave * 4096;  // 64x64 per wave (8KB), 8x8KB = 64KB
    #pragma unroll
    for (int p = 0; p < 2; ++p) {
      // round p: rows 64p..64p+63 of this wave's 128-row tile
      #pragma unroll
      for (int mi = 0; mi < 4; ++mi)
        #pragma unroll
        for (int ni = 0; ni < 4; ++ni)
          #pragma unroll
          for (int r = 0; r < 4; ++r)
            Cw[(mi * 16 + quad * 4 + r) * 64 + ni * 16 + lrow] = f2bf(acc[p * 4 + mi][ni][r]);
      #pragma unroll
      for (int it = 0; it < 8; ++it) {
        int row = it * 8 + (lane >> 3);
        int c8  = (lane & 7) * 8;
        int grow = row0 + wm + p * 64 + row;
        if (grow < M) {
          int4v v = *(const int4v*)(Cw + row * 64 + c8);
          *(int4v*)(C + (size_t)grow * N + col0 + wn + c8) = v;
        }
      }
    }
  }
}

// ---------------- fused attention over 87 keys (QBLK=128, 8 waves) ---------
// Q: 65536 x 1280 ([tq|vq]); KV: 1392 x 2560; VtG: [b][h][80][96]; O: 65536x640
// Grid: (qtile=128 rows, h=8, b=16), 512 threads = 8 waves x 16 q-rows.
// LDS: Ke 96x168 (32256 B) + Vt 80x104 (16640 B) = 48896 B.
// P (128 x PS = 26624 B) overlays Ke after scores.
__global__ __launch_bounds__(512, 4) void attn_kernel(
    const unsigned short* __restrict__ Q,
    const unsigned short* __restrict__ KV,
    const unsigned short* __restrict__ VtG,
    unsigned short* __restrict__ O) {
  constexpr int KS = 168;   // Ke row stride (shorts)
  constexpr int PS = 104;   // P / Vt row stride
  __shared__ __align__(16) unsigned short smem[96 * KS + 80 * PS];
  unsigned short* Ke = smem;              // 96 x KS
  unsigned short* Vt = smem + 96 * KS;    // 80 x PS
  unsigned short* P  = smem;              // 128 x PS overlay on Ke

  const int tid = threadIdx.x;
  const int wave = tid >> 6, lane = tid & 63;
  const int lrow = lane & 15, quad = lane >> 4;
  const int qt = blockIdx.x, h = blockIdx.y, b = blockIdx.z;
  const size_t qbase = (size_t)(b * 4096 + qt * 128);

  // stage Vt (coalesced from VtG): 80 rows x 12 chunks
  const unsigned short* vg = VtG + (size_t)(b * 8 + h) * 80 * 96;
  for (int idx = tid; idx < 80 * 12; idx += 512) {
    int r = idx / 12, c = idx % 12;
    *(int4v*)(Vt + r * PS + c * 8) = *(const int4v*)(vg + r * 96 + c * 8);
  }
  // stage Ke: text keys -> [Ktext | 0], visual keys -> [0 | Kvis], pad rows = 0
  for (int idx = tid; idx < 96 * 20; idx += 512) {
    int r = idx / 20, c = idx % 20;
    int4v v = {0, 0, 0, 0};
    if (r < 87) {
      if (r < 77 && c < 10)
        v = *(const int4v*)(KV + (size_t)(b * 87 + r) * 2560 + h * 80 + c * 8);
      else if (r >= 77 && c >= 10)
        v = *(const int4v*)(KV + (size_t)(b * 87 + r) * 2560 + 1280 + h * 80 + (c - 10) * 8);
    }
    *(int4v*)(Ke + r * KS + c * 8) = v;
  }

  // Q A-fragments straight from global (16B/lane, each wave owns its 16 rows)
  const unsigned short* Qrow = Q + (qbase + wave * 16 + lrow) * 1280;
  short8 qfrag[5];
  #pragma unroll
  for (int kc = 0; kc < 5; ++kc) {
    int j = kc * 32 + quad * 8;                  // 0..152
    int gcol = h * 80 + j + (j >= 80 ? 560 : 0); // tq half vs vq half
    qfrag[kc] = *(const short8*)(Qrow + gcol);
  }
  __syncthreads();

  // scores S = Q * Ke^T : wave = 16 q-rows x 96 key-cols
  f32x4 zero = {0.f, 0.f, 0.f, 0.f};
  f32x4 s[6];
  #pragma unroll
  for (int nt = 0; nt < 6; ++nt) s[nt] = zero;
  #pragma unroll
  for (int kc = 0; kc < 5; ++kc) {
    #pragma unroll
    for (int nt = 0; nt < 6; ++nt) {
      short8 bb = *(const short8*)(Ke + (nt * 16 + lrow) * KS + kc * 32 + quad * 8);
      s[nt] = __builtin_amdgcn_mfma_f32_16x16x32_bf16(qfrag[kc], bb, s[nt], 0, 0, 0);
    }
  }

  // softmax over 87 valid key-cols; lane holds rows quad*4+r, col nt*16+lrow
  const float scale = 0.11180339887498949f;  // 1/sqrt(80)
  float mrow[4] = {-1e30f, -1e30f, -1e30f, -1e30f};
  #pragma unroll
  for (int nt = 0; nt < 6; ++nt) {
    bool valid = (nt * 16 + lrow) < 87;
    #pragma unroll
    for (int r = 0; r < 4; ++r) {
      float v = valid ? s[nt][r] * scale : -1e30f;
      s[nt][r] = v;
      mrow[r] = fmaxf(mrow[r], v);
    }
  }
  #pragma unroll
  for (int off = 1; off < 16; off <<= 1)
    #pragma unroll
    for (int r = 0; r < 4; ++r)
      mrow[r] = fmaxf(mrow[r], __shfl_xor(mrow[r], off, 64));
  float lsum[4] = {0.f, 0.f, 0.f, 0.f};
  #pragma unroll
  for (int nt = 0; nt < 6; ++nt)
    #pragma unroll
    for (int r = 0; r < 4; ++r) {
      float p = __expf(s[nt][r] - mrow[r]);
      s[nt][r] = p;
      lsum[r] += p;
    }
  #pragma unroll
  for (int off = 1; off < 16; off <<= 1)
    #pragma unroll
    for (int r = 0; r < 4; ++r)
      lsum[r] += __shfl_xor(lsum[r], off, 64);
  float inv[4];
  #pragma unroll
  for (int r = 0; r < 4; ++r) inv[r] = 1.0f / lsum[r];

  __syncthreads();  // all waves done reading Ke before P overlays it

  // write P (128 x 96 bf16, stride PS) into Ke region — each wave its own rows
  #pragma unroll
  for (int nt = 0; nt < 6; ++nt)
    #pragma unroll
    for (int r = 0; r < 4; ++r)
      P[(wave * 16 + quad * 4 + r) * PS + nt * 16 + lrow] = f2bf(s[nt][r] * inv[r]);

  // O = P * V : 128 x 80, K = 96 (wave reads only its own P rows -> no barrier)
  f32x4 o[5];
  #pragma unroll
  for (int nt = 0; nt < 5; ++nt) o[nt] = zero;
  #pragma unroll
  for (int kc = 0; kc < 3; ++kc) {
    short8 a = *(const short8*)(P + (wave * 16 + lrow) * PS + kc * 32 + quad * 8);
    #pragma unroll
    for (int nt = 0; nt < 5; ++nt) {
      short8 bb = *(const short8*)(Vt + (nt * 16 + lrow) * PS + kc * 32 + quad * 8);
      o[nt] = __builtin_amdgcn_mfma_f32_16x16x32_bf16(a, bb, o[nt], 0, 0, 0);
    }
  }

  // wave-local transpose through own P rows -> coalesced 16B stores
  unsigned short* Ow = P + wave * 16 * PS;
  #pragma unroll
  for (int nt = 0; nt < 5; ++nt)
    #pragma unroll
    for (int r = 0; r < 4; ++r)
      Ow[(quad * 4 + r) * PS + nt * 16 + lrow] = f2bf(o[nt][r]);
  for (int idx = lane; idx < 160; idx += 64) {
    int r = idx / 10, c = idx % 10;
    *(int4v*)(O + (qbase + wave * 16 + r) * 640 + h * 80 + c * 8) =
        *(const int4v*)(Ow + r * PS + c * 8);
  }
}

// ---------------- host ----------------
extern "C" void kernel_launch(void* const* d_in, const int* in_sizes, int n_in,
                              void* d_out, int out_size, void* d_ws, size_t ws_size,
                              hipStream_t stream) {
  const float* x   = (const float*)d_in[0];
  const float* enc = (const float*)d_in[1];
  const float* Wq  = (const float*)d_in[2];
  const float* Wvq = (const float*)d_in[3];
  const float* Wk  = (const float*)d_in[4];
  const float* Wv  = (const float*)d_in[5];
  const float* Wvk = (const float*)d_in[6];
  const float* Wvv = (const float*)d_in[7];
  const float* Wo  = (const float*)d_in[8];
  const float* bo  = (const float*)d_in[9];
  float* out = (float*)d_out;
  char* ws = (char*)d_ws;

  // workspace layout (bytes)
  unsigned short* Qall  = (unsigned short*)(ws);                  // 65536x1280 bf16
  unsigned short* xbf   = (unsigned short*)(ws + 167772160ull);   // 65536x640 (reused as O)
  unsigned short* encbf = (unsigned short*)(ws + 251658240ull);   // 1392x768
  unsigned short* KVall = (unsigned short*)(ws + 253796352ull);   // 1392x2560
  unsigned short* WqcT  = (unsigned short*)(ws + 260923392ull);   // 1280x640
  unsigned short* WkvT  = (unsigned short*)(ws + 262561792ull);   // 2560x768 (dead after KV gemm)
  unsigned short* WoT   = (unsigned short*)(ws + 266493952ull);   // 640x640
  unsigned short* VtG   = WkvT;  // 16*8*80*96 bf16 = 1.97 MB, overlays dead WkvT

  // x + enc conversion in one launch
  cvt2_kernel<<<40960 + 1044, 256, 0, stream>>>(x, xbf, 40960, enc, encbf, 1069056);

  // all 7 weight transposes in one launch
  transpose_cvt7_kernel<<<dim3(24, 20, 7), 256, 0, stream>>>(
      Wq, Wvq, Wk, Wv, Wvk, Wvv, Wo, WqcT, WkvT, WoT);

  // KV projections (small): proven 128-tile kernel
  gemm_bt_kernel<false><<<220, 256, 0, stream>>>(encbf, WkvT, KVall, nullptr, 1392, 2560, 768, 20);
  // V transpose for attention (overwrites WkvT region — KV gemm already done)
  vtrans_kernel<<<3840, 256, 0, stream>>>(KVall, VtG);
  // Q projections: [tq | vq], ring-2 256x256 kernel: 256 M-tiles x 5 N-tiles
  gemm256_kernel<false><<<1280, 512, 0, stream>>>(xbf, WqcT, Qall, nullptr, 65536, 1280, 640, 5);
  // fused attention -> O (reuses xbf region), QBLK=128
  attn_kernel<<<dim3(32, 8, 16), 512, 0, stream>>>(Qall, KVall, VtG, xbf);
  // output projection + bias: 256 M-tiles x 3 N-tiles (N=640 padded to 768)
  gemm256_kernel<true><<<768, 512, 0, stream>>>(xbf, WoT, out, bo, 65536, 640, 640, 3);
}

// Round 7
// 611.207 us; speedup vs baseline: 3.5351x; 3.5351x over previous
//
#include <hip/hip_runtime.h>

typedef __attribute__((ext_vector_type(8))) short short8;     // 8 x bf16 (4 VGPRs)
typedef __attribute__((ext_vector_type(4))) float f32x4;      // MFMA accum
typedef __attribute__((ext_vector_type(4))) int int4v;        // 16B mover

typedef const __attribute__((address_space(1))) void* gas_t;
typedef __attribute__((address_space(3))) void* las_t;

__device__ __forceinline__ unsigned short f2bf(float f) {
  unsigned int u = __float_as_uint(f);
  u += 0x7fffu + ((u >> 16) & 1u);   // RNE
  return (unsigned short)(u >> 16);
}

// ---------------- fp32 -> bf16 convert (x and enc in one launch) -----------
__global__ void cvt2_kernel(const float* __restrict__ x,
                            unsigned short* __restrict__ xo, int nxb,
                            const float* __restrict__ enc,
                            unsigned short* __restrict__ eo, int ne) {
  if ((int)blockIdx.x < nxb) {
    int i = (blockIdx.x * 256 + threadIdx.x) * 4;
    float4 v = *(const float4*)(x + i);
    ushort4 r;
    r.x = f2bf(v.x); r.y = f2bf(v.y); r.z = f2bf(v.z); r.w = f2bf(v.w);
    *(ushort4*)(xo + i) = r;
  } else {
    int i = ((blockIdx.x - nxb) * 256 + threadIdx.x) * 4;
    if (i + 3 < ne) {
      float4 v = *(const float4*)(enc + i);
      ushort4 r;
      r.x = f2bf(v.x); r.y = f2bf(v.y); r.z = f2bf(v.z); r.w = f2bf(v.w);
      *(ushort4*)(eo + i) = r;
    }
  }
}

// ---------------- all 7 weight transposes in one launch --------------------
__global__ void transpose_cvt7_kernel(
    const float* __restrict__ W0, const float* __restrict__ W1,
    const float* __restrict__ W2, const float* __restrict__ W3,
    const float* __restrict__ W4, const float* __restrict__ W5,
    const float* __restrict__ W6,
    unsigned short* __restrict__ WqcT, unsigned short* __restrict__ WkvT,
    unsigned short* __restrict__ WoT) {
  const float* W; unsigned short* Wt; int K;
  switch (blockIdx.z) {
    case 0: W = W0; Wt = WqcT;            K = 640; break;
    case 1: W = W1; Wt = WqcT + 640*640;  K = 640; break;
    case 2: W = W2; Wt = WkvT;            K = 768; break;
    case 3: W = W3; Wt = WkvT + 640*768;  K = 768; break;
    case 4: W = W4; Wt = WkvT + 1280*768; K = 768; break;
    case 5: W = W5; Wt = WkvT + 1920*768; K = 768; break;
    default: W = W6; Wt = WoT;            K = 640; break;
  }
  const int N = 640;
  int k0 = blockIdx.x * 32, n0 = blockIdx.y * 32;
  if (k0 >= K) return;   // block-uniform, before any barrier
  __shared__ float t[32][33];
  int tx = threadIdx.x & 31, ty = threadIdx.x >> 5;   // 32 x 8
  #pragma unroll
  for (int i = 0; i < 32; i += 8)
    t[ty + i][tx] = W[(size_t)(k0 + ty + i) * N + n0 + tx];
  __syncthreads();
  #pragma unroll
  for (int i = 0; i < 32; i += 8)
    Wt[(size_t)(n0 + ty + i) * K + k0 + tx] = f2bf(t[tx][ty + i]);
}

// ---------------- V transpose: KVall -> VtG[b][h][d=80][k=96] ----------------
__global__ void vtrans_kernel(const unsigned short* __restrict__ KV,
                              unsigned short* __restrict__ VtG) {
  int idx = blockIdx.x * 256 + threadIdx.x;
  if (idx >= 16 * 8 * 80 * 96) return;
  int k = idx % 96;
  int d = (idx / 96) % 80;
  int h = (idx / (96 * 80)) % 8;
  int b = idx / (96 * 80 * 8);
  unsigned short v = 0;
  if (k < 87) {
    int base = (k < 77) ? 640 : 1920;  // tv at col 640, vv at col 1920
    v = KV[(size_t)(b * 87 + k) * 2560 + base + h * 80 + d];
  }
  VtG[idx] = v;
}

// ---------------- m97-style GEMM (kept for the small KV projection) --------
template<bool F32OUT>
__global__ __launch_bounds__(256, 2) void gemm_bt_kernel(
    const unsigned short* __restrict__ A,   // M x K bf16
    const unsigned short* __restrict__ Bt,  // N x K bf16
    void* __restrict__ Cptr, const float* __restrict__ bias,
    int M, int N, int K, int NT) {          // NT = number of 128-col tiles
  __shared__ __align__(16) unsigned short smem[2 * 128 * 64];
  unsigned short* As = smem;             // 128 x 64
  unsigned short* Bs = smem + 128 * 64;  // 128 x 64 (rows = n)

  const int tid  = threadIdx.x;
  const int wave = tid >> 6, lane = tid & 63;
  const int lrow = lane & 15, quad = lane >> 4;

  const int nwg = gridDim.x;
  const int qch = nwg >> 3, rch = nwg & 7;
  const int xcd = blockIdx.x & 7;
  const int wgid = (xcd < rch ? xcd * (qch + 1)
                              : rch * (qch + 1) + (xcd - rch) * qch)
                 + (blockIdx.x >> 3);
  const int row0 = (wgid / NT) * 128, col0 = (wgid % NT) * 128;

  const int wm = (wave >> 1) * 64, wn = (wave & 1) * 64;
  const int srow = lane >> 3;          // row within 8-row group
  const int scol = (lane & 7) * 8;     // bf16 col (16B chunk)

  f32x4 zero = {0.f, 0.f, 0.f, 0.f};
  f32x4 acc[4][4];
  #pragma unroll
  for (int mi = 0; mi < 4; ++mi)
    #pragma unroll
    for (int ni = 0; ni < 4; ++ni) acc[mi][ni] = zero;

  for (int k0 = 0; k0 < K; k0 += 64) {
    #pragma unroll
    for (int i = 0; i < 4; ++i) {
      int r = (wave * 4 + i) * 8 + srow;            // 0..127
      int ga = row0 + r; if (ga > M - 1) ga = M - 1; // clamp M edge
      const unsigned short* gA = A + (size_t)ga * K + k0 + scol;
      __builtin_amdgcn_global_load_lds((gas_t)gA, (las_t)(As + r * 64 + scol), 16, 0, 0);
      const unsigned short* gB = Bt + (size_t)(col0 + r) * K + k0 + scol;
      __builtin_amdgcn_global_load_lds((gas_t)gB, (las_t)(Bs + r * 64 + scol), 16, 0, 0);
    }
    __syncthreads();
    #pragma unroll
    for (int kk = 0; kk < 64; kk += 32) {
      short8 av[4], bv[4];
      #pragma unroll
      for (int mi = 0; mi < 4; ++mi)
        av[mi] = *(const short8*)(As + (wm + mi * 16 + lrow) * 64 + kk + quad * 8);
      #pragma unroll
      for (int ni = 0; ni < 4; ++ni)
        bv[ni] = *(const short8*)(Bs + (wn + ni * 16 + lrow) * 64 + kk + quad * 8);
      #pragma unroll
      for (int mi = 0; mi < 4; ++mi)
        #pragma unroll
        for (int ni = 0; ni < 4; ++ni)
          acc[mi][ni] = __builtin_amdgcn_mfma_f32_16x16x32_bf16(av[mi], bv[ni], acc[mi][ni], 0, 0, 0);
    }
    __syncthreads();
  }

  if (F32OUT) {
    float* C = (float*)Cptr;
    #pragma unroll
    for (int mi = 0; mi < 4; ++mi)
      #pragma unroll
      for (int ni = 0; ni < 4; ++ni) {
        int col = col0 + wn + ni * 16 + lrow;
        float bv = bias[col];
        #pragma unroll
        for (int r = 0; r < 4; ++r) {
          int row = row0 + wm + mi * 16 + quad * 4 + r;
          if (row < M) C[(size_t)row * N + col] = acc[mi][ni][r] + bv;
        }
      }
  } else {
    unsigned short* C = (unsigned short*)Cptr;
    unsigned short* Cw = smem + wave * 4096;  // 64x64 region per wave
    #pragma unroll
    for (int mi = 0; mi < 4; ++mi)
      #pragma unroll
      for (int ni = 0; ni < 4; ++ni)
        #pragma unroll
        for (int r = 0; r < 4; ++r)
          Cw[(mi * 16 + quad * 4 + r) * 64 + ni * 16 + lrow] = f2bf(acc[mi][ni][r]);
    #pragma unroll
    for (int it = 0; it < 8; ++it) {
      int row = it * 8 + (lane >> 3);
      int c8  = (lane & 7) * 8;
      int grow = row0 + wm + row;
      if (grow < M) {
        int4v v = *(const int4v*)(Cw + row * 64 + c8);
        *(int4v*)(C + (size_t)grow * N + col0 + wn + c8) = v;
      }
    }
  }
}

// ---------------- 256x256 GEMM, ring-4 (128KB LDS) — round-2 config --------
// 512 threads = 8 waves (2M x 4N), per-wave 128x64 output, BK=32.
// Best measured config (r2: Q GEMM 140us, MfmaUtil 32%, VGPR 96, no spill).
// Stage tile t+3 while computing tile t; ONE barrier + counted vmcnt(8)
// per K-tile (never 0 in steady state). st_16x32 LDS swizzle via
// pre-swizzled global source (rule #21); bijective XCD swizzle.
// NOTE: (512, 2) NOT higher — 8-wave 256^2 needs ~190 unified regs/wave;
// capping at 128 (r6's (512,4)) spills acc to scratch: 4.5 GB HBM, 7.7x slower.
template<bool F32OUT>
__global__ __launch_bounds__(512, 2) void gemm256_kernel(
    const unsigned short* __restrict__ A,   // M x K bf16
    const unsigned short* __restrict__ Bt,  // N x K bf16
    void* __restrict__ Cptr, const float* __restrict__ bias,
    int M, int N, int K, int NT) {          // NT = number of 256-col tiles
  __shared__ __align__(16) unsigned short smem[4 * 16384];  // 128 KB

  const int tid  = threadIdx.x;
  const int wave = tid >> 6, lane = tid & 63;
  const int lrow = lane & 15, quad = lane >> 4;

  // bijective XCD-chunked swizzle, N-fast linearization
  const int nwg = gridDim.x;
  const int qch = nwg >> 3, rch = nwg & 7;
  const int xcd = blockIdx.x & 7;
  const int wgid = (xcd < rch ? xcd * (qch + 1)
                              : rch * (qch + 1) + (xcd - rch) * qch)
                 + (blockIdx.x >> 3);
  const int row0 = (wgid / NT) * 256, col0 = (wgid % NT) * 256;

  const int wm = (wave >> 2) * 128;   // 0 or 128
  const int wn = (wave & 3) * 64;     // 0..192
  const int NKT = K >> 5;             // K-tiles of 32 (assumed >= 3)

  // ---- staging source addresses (pre-swizzled global, linear LDS dest) ----
  const unsigned short* gA[2];
  const unsigned short* gB[2];
  #pragma unroll
  for (int j = 0; j < 2; ++j) {
    int P = tid * 16 + j * 8192;
    int lin = P ^ (((P >> 9) & 1) << 5);
    int r = ((P >> 10) << 4) + ((lin >> 6) & 15);   // logical row 0..255
    int c = (lin & 63) >> 1;                        // logical col 0..31
    int ga = row0 + r; if (ga > M - 1) ga = M - 1;
    int gb = col0 + r; if (gb > N - 1) gb = N - 1;  // clamp (O-gemm pad tile)
    gA[j] = A  + (size_t)ga * K + c;
    gB[j] = Bt + (size_t)gb * K + c;
  }

  // ---- fragment read offsets (shorts), with st_16x32 XOR ----
  const int xorb = ((lrow >> 3) & 1) << 4;   // byte-bit5 == short-bit4
  int offA[8], offB[4];
  #pragma unroll
  for (int mi = 0; mi < 8; ++mi)
    offA[mi] = (((((wm >> 4) + mi) << 9) + (lrow << 5) + (quad << 3))) ^ xorb;
  #pragma unroll
  for (int ni = 0; ni < 4; ++ni)
    offB[ni] = (((((wn >> 4) + ni) << 9) + (lrow << 5) + (quad << 3))) ^ xorb;

  f32x4 zero = {0.f, 0.f, 0.f, 0.f};
  f32x4 acc[8][4];
  #pragma unroll
  for (int mi = 0; mi < 8; ++mi)
    #pragma unroll
    for (int ni = 0; ni < 4; ++ni) acc[mi][ni] = zero;

  // ---- prologue: stage tiles 0..2 into ring slots 0..2 ----
  #pragma unroll
  for (int t = 0; t < 3; ++t) {
    unsigned short* slot = smem + (t & 3) * 16384;
    #pragma unroll
    for (int j = 0; j < 2; ++j)
      __builtin_amdgcn_global_load_lds((gas_t)(gA[j] + t * 32),
          (las_t)(slot + j * 4096 + tid * 8), 16, 0, 0);
    #pragma unroll
    for (int j = 0; j < 2; ++j)
      __builtin_amdgcn_global_load_lds((gas_t)(gB[j] + t * 32),
          (las_t)(slot + 8192 + j * 4096 + tid * 8), 16, 0, 0);
  }

  // ---- main loop: one barrier + one counted vmcnt per K-tile ----
  for (int t = 0; t < NKT; ++t) {
    if (t + 2 < NKT)      asm volatile("s_waitcnt vmcnt(8)" ::: "memory");
    else if (t + 1 < NKT) asm volatile("s_waitcnt vmcnt(4)" ::: "memory");
    else                  asm volatile("s_waitcnt vmcnt(0)" ::: "memory");
    asm volatile("s_barrier" ::: "memory");

    const unsigned short* As = smem + (t & 3) * 16384;
    const unsigned short* Bs = As + 8192;
    const bool pf = (t + 3 < NKT);
    unsigned short* nslot = smem + ((t + 3) & 3) * 16384;

    // phase 0: quadrant mi 0..3 (all ni), prefetch next A half
    short8 av0[4], bv[4];
    #pragma unroll
    for (int mi = 0; mi < 4; ++mi) av0[mi] = *(const short8*)(As + offA[mi]);
    #pragma unroll
    for (int ni = 0; ni < 4; ++ni) bv[ni] = *(const short8*)(Bs + offB[ni]);
    if (pf) {
      #pragma unroll
      for (int j = 0; j < 2; ++j)
        __builtin_amdgcn_global_load_lds((gas_t)(gA[j] + (t + 3) * 32),
            (las_t)(nslot + j * 4096 + tid * 8), 16, 0, 0);
    }
    __builtin_amdgcn_s_setprio(1);
    #pragma unroll
    for (int mi = 0; mi < 4; ++mi)
      #pragma unroll
      for (int ni = 0; ni < 4; ++ni)
        acc[mi][ni] = __builtin_amdgcn_mfma_f32_16x16x32_bf16(av0[mi], bv[ni], acc[mi][ni], 0, 0, 0);
    __builtin_amdgcn_s_setprio(0);

    // phase 1: quadrant mi 4..7, prefetch next B half
    short8 av1[4];
    #pragma unroll
    for (int mi = 0; mi < 4; ++mi) av1[mi] = *(const short8*)(As + offA[4 + mi]);
    if (pf) {
      #pragma unroll
      for (int j = 0; j < 2; ++j)
        __builtin_amdgcn_global_load_lds((gas_t)(gB[j] + (t + 3) * 32),
            (las_t)(nslot + 8192 + j * 4096 + tid * 8), 16, 0, 0);
    }
    __builtin_amdgcn_s_setprio(1);
    #pragma unroll
    for (int mi = 0; mi < 4; ++mi)
      #pragma unroll
      for (int ni = 0; ni < 4; ++ni)
        acc[4 + mi][ni] = __builtin_amdgcn_mfma_f32_16x16x32_bf16(av1[mi], bv[ni], acc[4 + mi][ni], 0, 0, 0);
    __builtin_amdgcn_s_setprio(0);
  }

  // ---- epilogue ----
  if (F32OUT) {
    float* C = (float*)Cptr;
    #pragma unroll
    for (int mi = 0; mi < 8; ++mi)
      #pragma unroll
      for (int ni = 0; ni < 4; ++ni) {
        int col = col0 + wn + ni * 16 + lrow;
        int colc = col < N ? col : 0;
        float bval = bias[colc];
        #pragma unroll
        for (int r = 0; r < 4; ++r) {
          int row = row0 + wm + mi * 16 + quad * 4 + r;
          if (col < N && row < M)
            C[(size_t)row * N + col] = acc[mi][ni][r] + bval;
        }
      }
  } else {
    asm volatile("s_barrier" ::: "memory");   // all waves done with ring LDS
    unsigned short* C = (unsigned short*)Cptr;
    unsigned short* Cw = smem + wave * 8192;  // 128x64 bf16 per wave (16KB)
    #pragma unroll
    for (int mi = 0; mi < 8; ++mi)
      #pragma unroll
      for (int ni = 0; ni < 4; ++ni)
        #pragma unroll
        for (int r = 0; r < 4; ++r)
          Cw[(mi * 16 + quad * 4 + r) * 64 + ni * 16 + lrow] = f2bf(acc[mi][ni][r]);
    #pragma unroll
    for (int it = 0; it < 16; ++it) {
      int row = it * 8 + (lane >> 3);
      int c8  = (lane & 7) * 8;
      int grow = row0 + wm + row;
      if (grow < M) {
        int4v v = *(const int4v*)(Cw + row * 64 + c8);
        *(int4v*)(C + (size_t)grow * N + col0 + wn + c8) = v;
      }
    }
  }
}

// ---------------- fused attention over 87 keys (QBLK=128, 8 waves) ---------
// Q: 65536 x 1280 ([tq|vq]); KV: 1392 x 2560; VtG: [b][h][80][96]; O: 65536x640
// Grid: (qtile=128 rows, h=8, b=16), 512 threads = 8 waves x 16 q-rows.
// LDS: Ke 96x168 (32256 B) + Vt 80x104 (16640 B) = 48896 B.
// P (128 x PS = 26624 B) overlays Ke after scores. (512,4): ~100 regs fit 128.
__global__ __launch_bounds__(512, 4) void attn_kernel(
    const unsigned short* __restrict__ Q,
    const unsigned short* __restrict__ KV,
    const unsigned short* __restrict__ VtG,
    unsigned short* __restrict__ O) {
  constexpr int KS = 168;   // Ke row stride (shorts)
  constexpr int PS = 104;   // P / Vt row stride
  __shared__ __align__(16) unsigned short smem[96 * KS + 80 * PS];
  unsigned short* Ke = smem;              // 96 x KS
  unsigned short* Vt = smem + 96 * KS;    // 80 x PS
  unsigned short* P  = smem;              // 128 x PS overlay on Ke

  const int tid = threadIdx.x;
  const int wave = tid >> 6, lane = tid & 63;
  const int lrow = lane & 15, quad = lane >> 4;
  const int qt = blockIdx.x, h = blockIdx.y, b = blockIdx.z;
  const size_t qbase = (size_t)(b * 4096 + qt * 128);

  // stage Vt (coalesced from VtG): 80 rows x 12 chunks
  const unsigned short* vg = VtG + (size_t)(b * 8 + h) * 80 * 96;
  for (int idx = tid; idx < 80 * 12; idx += 512) {
    int r = idx / 12, c = idx % 12;
    *(int4v*)(Vt + r * PS + c * 8) = *(const int4v*)(vg + r * 96 + c * 8);
  }
  // stage Ke: text keys -> [Ktext | 0], visual keys -> [0 | Kvis], pad rows = 0
  for (int idx = tid; idx < 96 * 20; idx += 512) {
    int r = idx / 20, c = idx % 20;
    int4v v = {0, 0, 0, 0};
    if (r < 87) {
      if (r < 77 && c < 10)
        v = *(const int4v*)(KV + (size_t)(b * 87 + r) * 2560 + h * 80 + c * 8);
      else if (r >= 77 && c >= 10)
        v = *(const int4v*)(KV + (size_t)(b * 87 + r) * 2560 + 1280 + h * 80 + (c - 10) * 8);
    }
    *(int4v*)(Ke + r * KS + c * 8) = v;
  }

  // Q A-fragments straight from global (16B/lane, each wave owns its 16 rows)
  const unsigned short* Qrow = Q + (qbase + wave * 16 + lrow) * 1280;
  short8 qfrag[5];
  #pragma unroll
  for (int kc = 0; kc < 5; ++kc) {
    int j = kc * 32 + quad * 8;                  // 0..152
    int gcol = h * 80 + j + (j >= 80 ? 560 : 0); // tq half vs vq half
    qfrag[kc] = *(const short8*)(Qrow + gcol);
  }
  __syncthreads();

  // scores S = Q * Ke^T : wave = 16 q-rows x 96 key-cols
  f32x4 zero = {0.f, 0.f, 0.f, 0.f};
  f32x4 s[6];
  #pragma unroll
  for (int nt = 0; nt < 6; ++nt) s[nt] = zero;
  #pragma unroll
  for (int kc = 0; kc < 5; ++kc) {
    #pragma unroll
    for (int nt = 0; nt < 6; ++nt) {
      short8 bb = *(const short8*)(Ke + (nt * 16 + lrow) * KS + kc * 32 + quad * 8);
      s[nt] = __builtin_amdgcn_mfma_f32_16x16x32_bf16(qfrag[kc], bb, s[nt], 0, 0, 0);
    }
  }

  // softmax over 87 valid key-cols; lane holds rows quad*4+r, col nt*16+lrow
  const float scale = 0.11180339887498949f;  // 1/sqrt(80)
  float mrow[4] = {-1e30f, -1e30f, -1e30f, -1e30f};
  #pragma unroll
  for (int nt = 0; nt < 6; ++nt) {
    bool valid = (nt * 16 + lrow) < 87;
    #pragma unroll
    for (int r = 0; r < 4; ++r) {
      float v = valid ? s[nt][r] * scale : -1e30f;
      s[nt][r] = v;
      mrow[r] = fmaxf(mrow[r], v);
    }
  }
  #pragma unroll
  for (int off = 1; off < 16; off <<= 1)
    #pragma unroll
    for (int r = 0; r < 4; ++r)
      mrow[r] = fmaxf(mrow[r], __shfl_xor(mrow[r], off, 64));
  float lsum[4] = {0.f, 0.f, 0.f, 0.f};
  #pragma unroll
  for (int nt = 0; nt < 6; ++nt)
    #pragma unroll
    for (int r = 0; r < 4; ++r) {
      float p = __expf(s[nt][r] - mrow[r]);
      s[nt][r] = p;
      lsum[r] += p;
    }
  #pragma unroll
  for (int off = 1; off < 16; off <<= 1)
    #pragma unroll
    for (int r = 0; r < 4; ++r)
      lsum[r] += __shfl_xor(lsum[r], off, 64);
  float inv[4];
  #pragma unroll
  for (int r = 0; r < 4; ++r) inv[r] = 1.0f / lsum[r];

  __syncthreads();  // all waves done reading Ke before P overlays it

  // write P (128 x 96 bf16, stride PS) into Ke region — each wave its own rows
  #pragma unroll
  for (int nt = 0; nt < 6; ++nt)
    #pragma unroll
    for (int r = 0; r < 4; ++r)
      P[(wave * 16 + quad * 4 + r) * PS + nt * 16 + lrow] = f2bf(s[nt][r] * inv[r]);

  // O = P * V : 128 x 80, K = 96 (wave reads only its own P rows -> no barrier)
  f32x4 o[5];
  #pragma unroll
  for (int nt = 0; nt < 5; ++nt) o[nt] = zero;
  #pragma unroll
  for (int kc = 0; kc < 3; ++kc) {
    short8 a = *(const short8*)(P + (wave * 16 + lrow) * PS + kc * 32 + quad * 8);
    #pragma unroll
    for (int nt = 0; nt < 5; ++nt) {
      short8 bb = *(const short8*)(Vt + (nt * 16 + lrow) * PS + kc * 32 + quad * 8);
      o[nt] = __builtin_amdgcn_mfma_f32_16x16x32_bf16(a, bb, o[nt], 0, 0, 0);
    }
  }

  // wave-local transpose through own P rows -> coalesced 16B stores
  unsigned short* Ow = P + wave * 16 * PS;
  #pragma unroll
  for (int nt = 0; nt < 5; ++nt)
    #pragma unroll
    for (int r = 0; r < 4; ++r)
      Ow[(quad * 4 + r) * PS + nt * 16 + lrow] = f2bf(o[nt][r]);
  for (int idx = lane; idx < 160; idx += 64) {
    int r = idx / 10, c = idx % 10;
    *(int4v*)(O + (qbase + wave * 16 + r) * 640 + h * 80 + c * 8) =
        *(const int4v*)(Ow + r * PS + c * 8);
  }
}

// ---------------- host ----------------
extern "C" void kernel_launch(void* const* d_in, const int* in_sizes, int n_in,
                              void* d_out, int out_size, void* d_ws, size_t ws_size,
                              hipStream_t stream) {
  const float* x   = (const float*)d_in[0];
  const float* enc = (const float*)d_in[1];
  const float* Wq  = (const float*)d_in[2];
  const float* Wvq = (const float*)d_in[3];
  const float* Wk  = (const float*)d_in[4];
  const float* Wv  = (const float*)d_in[5];
  const float* Wvk = (const float*)d_in[6];
  const float* Wvv = (const float*)d_in[7];
  const float* Wo  = (const float*)d_in[8];
  const float* bo  = (const float*)d_in[9];
  float* out = (float*)d_out;
  char* ws = (char*)d_ws;

  // workspace layout (bytes)
  unsigned short* Qall  = (unsigned short*)(ws);                  // 65536x1280 bf16
  unsigned short* xbf   = (unsigned short*)(ws + 167772160ull);   // 65536x640 (reused as O)
  unsigned short* encbf = (unsigned short*)(ws + 251658240ull);   // 1392x768
  unsigned short* KVall = (unsigned short*)(ws + 253796352ull);   // 1392x2560
  unsigned short* WqcT  = (unsigned short*)(ws + 260923392ull);   // 1280x640
  unsigned short* WkvT  = (unsigned short*)(ws + 262561792ull);   // 2560x768 (dead after KV gemm)
  unsigned short* WoT   = (unsigned short*)(ws + 266493952ull);   // 640x640
  unsigned short* VtG   = WkvT;  // 16*8*80*96 bf16 = 1.97 MB, overlays dead WkvT

  // x + enc conversion in one launch
  cvt2_kernel<<<40960 + 1044, 256, 0, stream>>>(x, xbf, 40960, enc, encbf, 1069056);

  // all 7 weight transposes in one launch
  transpose_cvt7_kernel<<<dim3(24, 20, 7), 256, 0, stream>>>(
      Wq, Wvq, Wk, Wv, Wvk, Wvv, Wo, WqcT, WkvT, WoT);

  // KV projections (small): proven 128-tile kernel
  gemm_bt_kernel<false><<<220, 256, 0, stream>>>(encbf, WkvT, KVall, nullptr, 1392, 2560, 768, 20);
  // V transpose for attention (overwrites WkvT region — KV gemm already done)
  vtrans_kernel<<<3840, 256, 0, stream>>>(KVall, VtG);
  // Q projections: [tq | vq], ring-4 256x256 kernel: 256 M-tiles x 5 N-tiles
  gemm256_kernel<false><<<1280, 512, 0, stream>>>(xbf, WqcT, Qall, nullptr, 65536, 1280, 640, 5);
  // fused attention -> O (reuses xbf region), QBLK=128
  attn_kernel<<<dim3(32, 8, 16), 512, 0, stream>>>(Qall, KVall, VtG, xbf);
  // output projection + bias: 256 M-tiles x 3 N-tiles (N=640 padded to 768)
  gemm256_kernel<true><<<768, 512, 0, stream>>>(xbf, WoT, out, bo, 65536, 640, 640, 3);
}